// Round 2
// baseline (129.870 us; speedup 1.0000x reference)
//
#include <hip/hip_runtime.h>
#include <math.h>

#define BDIM 8
#define NDIM 128
#define TDIM 1024
#define TPB 512
#define ROWS_PER_BLOCK 8   // one row per wave; 8 waves per block

#define EPS_F 1e-12f
#define RHO_LIM_F (1.0f - 1e-6f)
#define PI_F 3.14159265358979323846f

// native vector type for nontemporal builtins (HIP_vector_type is rejected)
typedef float nfloat4 __attribute__((ext_vector_type(4)));

// Fast path identity (exact for all p >= 0 incl. p < eps):
//   p * clamp(kgp / max(p,eps), -RHO, RHO) == clamp(kgp, -p*RHO, p*RHO)
// so when one_m == (1-a)^2 == 0:  c0 = hc * med3(kgp, -p*RHO, p*RHO), no rcp.
__device__ __forceinline__ void kfun2(float kgp, float kntk, float sx, float sy,
                                      float one_m, float coef, bool fast,
                                      float& c0, float& cn)
{
    const float inv2pi = 0.15915494309189535f;
    const float p = sx * sy;   // matches reference std_x*std_y
    if (fast) {
        const float hc = 0.5f * coef;
        const float pr = p * RHO_LIM_F;
        c0 = hc * fminf(fmaxf(kgp, -pr), pr);   // v_med3_f32
        cn = hc * kntk;
    } else {
        const float r  = fminf(fmaxf(kgp * __builtin_amdgcn_rcpf(fmaxf(p, EPS_F)), -RHO_LIM_F), RHO_LIM_F);
        const float th = acosf(r);
        const float s  = sqrtf(1.0f - r * r);
        const float br = coef * PI_F - one_m * th;
        c0 = p * inv2pi * (one_m * s + r * br);
        cn = br * inv2pi * kntk;
    }
}

__global__ __launch_bounds__(TPB) void conv_arccos_kernel(
    const float* __restrict__ k,      // (B,B,N,T,2)
    const float* __restrict__ leak,   // scalar
    const float* __restrict__ alpha,  // (3,)
    const float* __restrict__ beta,   // scalar
    float* __restrict__ out)          // (B,B,N,T,2)
{
    const int wid  = threadIdx.x >> 6;
    const int lane = threadIdx.x & 63;
    const int row  = blockIdx.x * ROWS_PER_BLOCK + wid;  // flat (b1,b2,n)
    const int n    = row & (NDIM - 1);
    const int bb   = row >> 7;                           // / NDIM
    const int b2   = bb & (BDIM - 1);
    const int b1   = bb >> 3;

    // forward value of clamp_pg(x) is max(x, 0)
    const float a   = fmaxf(leak[0], 0.0f);
    const float w0  = fmaxf(alpha[0], 0.0f);
    const float w1  = fmaxf(alpha[1], 0.0f);
    const float w2  = fmaxf(alpha[2], 0.0f);
    const float bia = fmaxf(beta[0], 0.0f);

    const float one_m = (1.0f - a) * (1.0f - a);
    const float coef  = 1.0f + a * a;
    const bool  fast  = (one_m == 0.0f);

    // this wave's row of k / out, as nfloat4 = (kgp[t],kntk[t],kgp[t+1],kntk[t+1])
    const nfloat4* krow = (const nfloat4*)(k + (size_t)row * TDIM * 2);
    nfloat4*       orow = (nfloat4*)(out + (size_t)row * TDIM * 2);
    // v[b,t] = k[b,b,0,t,0]
    const float2* vrx = (const float2*)k + (size_t)(b1 * BDIM + b1) * NDIM * TDIM;
    const float2* vry = (const float2*)k + (size_t)(b2 * BDIM + b2) * NDIM * TDIM;

    // compute c0/cn for pair p = m*64 + lane (elements t0=2p, t0+1)
    auto compute = [&](int m, float& c00, float& c01, float& cn0, float& cn1) {
        const int p  = (m << 6) + lane;
        const int t0 = p * 2;
        const nfloat4 kv = __builtin_nontemporal_load(&krow[p]);   // streamed once
        const float4 vx4 = *(const float4*)(vrx + t0);             // 16B aligned, L1/L2-hot
        const int e = n + t0;
        const float2 vya = vry[e];                                 // L1/L2-hot
        const float2 vyb = vry[e + 1];
        const float y0 = (e     < TDIM) ? vya.x : 0.0f;            // v_pad zero beyond T
        const float y1 = (e + 1 < TDIM) ? vyb.x : 0.0f;
        const float sx0 = sqrtf(fmaxf(vx4.x, 0.0f));
        const float sx1 = sqrtf(fmaxf(vx4.z, 0.0f));
        const float sy0 = sqrtf(fmaxf(y0, 0.0f));
        const float sy1 = sqrtf(fmaxf(y1, 0.0f));
        kfun2(kv.x, kv.y, sx0, sy0, one_m, coef, fast, c00, cn0);
        kfun2(kv.z, kv.w, sx1, sy1, one_m, coef, fast, c01, cn1);
    };

    float c00, c01, cn0, cn1;
    compute(0, c00, c01, cn0, cn1);
    float pe0 = 0.0f, pen = 0.0f;   // prev chunk lane-63 c01/cn1 (left pad = 0)

    #pragma unroll
    for (int m = 0; m < 8; ++m) {
        // software pipeline: produce chunk m+1 so lane 63 can take its lane-0 c00
        float n00 = 0.0f, n01 = 0.0f, nn0 = 0.0f, nn1 = 0.0f;
        if (m < 7) compute(m + 1, n00, n01, nn0, nn1);   // m==7: right pad = 0
        const float nx0 = __shfl(n00, 0);
        const float nxn = __shfl(nn0, 0);

        // halo exchange, pure intra-wave
        float c0l = __shfl_up(c01, 1);
        float cnl = __shfl_up(cn1, 1);
        if (lane == 0) { c0l = pe0; cnl = pen; }
        float c0r = __shfl_down(c00, 1);
        float cnr = __shfl_down(cn0, 1);
        if (lane == 63) { c0r = nx0; cnr = nxn; }

        // kg = conv(c0) + bia ; kn = conv(cn) + kg
        const float kg0 = fmaf(w0, c0l, fmaf(w1, c00, fmaf(w2, c01, bia)));
        const float kg1 = fmaf(w0, c00, fmaf(w1, c01, fmaf(w2, c0r, bia)));
        const float kn0 = fmaf(w0, cnl, fmaf(w1, cn0, fmaf(w2, cn1, kg0)));
        const float kn1 = fmaf(w0, cn0, fmaf(w1, cn1, fmaf(w2, cnr, kg1)));

        nfloat4 o;
        o.x = kg0; o.y = kn0; o.z = kg1; o.w = kn1;
        __builtin_nontemporal_store(o, &orow[(m << 6) + lane]);   // never re-read

        pe0 = __shfl(c01, 63);
        pen = __shfl(cn1, 63);
        c00 = n00; c01 = n01; cn0 = nn0; cn1 = nn1;
    }
}

extern "C" void kernel_launch(void* const* d_in, const int* in_sizes, int n_in,
                              void* d_out, int out_size, void* d_ws, size_t ws_size,
                              hipStream_t stream) {
    const float* k     = (const float*)d_in[0];
    const float* leak  = (const float*)d_in[1];
    const float* alpha = (const float*)d_in[2];
    const float* beta  = (const float*)d_in[3];
    float* out = (float*)d_out;

    const int n_blocks = BDIM * BDIM * NDIM / ROWS_PER_BLOCK;   // 1024
    conv_arccos_kernel<<<n_blocks, TPB, 0, stream>>>(k, leak, alpha, beta, out);
}

// Round 3
// 129.534 us; speedup vs baseline: 1.0026x; 1.0026x over previous
//
#include <hip/hip_runtime.h>
#include <math.h>

#define BDIM 8
#define NDIM 128
#define TDIM 1024
#define TPB 512    // one float4 (elements t,t+1) per thread per row
#define ROWS 4     // rows per block; same (b1,b2) per block, n0 multiple of 4

#define EPS_F 1e-12f
#define RHO_LIM_F (1.0f - 1e-6f)
#define PI_F 3.14159265358979323846f

// Fast path identity (exact for all p >= 0 incl. p < eps):
//   p * clamp(kgp / max(p,eps), -RHO, RHO) == clamp(kgp, -p*RHO, p*RHO)
// so when one_m == (1-a)^2 == 0:  c0 = hc * med3(kgp, -p*RHO, p*RHO), no rcp.
// Halo-pad elements are produced by passing sx = 0 AND k-pair = 0:
//   fast:  c0 = hc*clamp(0, -0, 0) = 0, cn = hc*0 = 0
//   slow:  p = 0 -> c0 = p*(...) = 0, cn = br*inv2pi*0 = 0
__device__ __forceinline__ void kfun(float kgp, float kntk, float sx, float sy,
                                     float one_m, float coef, bool fast,
                                     float& c0, float& cn)
{
    const float inv2pi = 0.15915494309189535f;
    const float p = sx * sy;   // std_x * std_y, as in reference
    if (fast) {
        const float hc = 0.5f * coef;
        const float pr = p * RHO_LIM_F;
        c0 = hc * fminf(fmaxf(kgp, -pr), pr);   // v_med3_f32
        cn = hc * kntk;
    } else {
        const float r  = fminf(fmaxf(kgp * __builtin_amdgcn_rcpf(fmaxf(p, EPS_F)), -RHO_LIM_F), RHO_LIM_F);
        const float th = acosf(r);
        const float s  = sqrtf(1.0f - r * r);
        const float br = coef * PI_F - one_m * th;
        c0 = p * inv2pi * (one_m * s + r * br);
        cn = br * inv2pi * kntk;
    }
}

__global__ __launch_bounds__(TPB) void conv_arccos_kernel(
    const float* __restrict__ k,      // (B,B,N,T,2)
    const float* __restrict__ leak,   // scalar
    const float* __restrict__ alpha,  // (3,)
    const float* __restrict__ beta,   // scalar
    float* __restrict__ out)          // (B,B,N,T,2)
{
    const int base = blockIdx.x * ROWS;   // first row of this block
    const int n0   = base % NDIM;         // n of first row (multiple of 4)
    const int bb   = base / NDIM;
    const int b2   = bb % BDIM;
    const int b1   = bb / BDIM;
    const int tid  = threadIdx.x;
    const int t    = tid * 2;             // first element index of this thread

    // forward value of clamp_pg(x) is max(x, 0)
    const float a   = fmaxf(leak[0], 0.0f);
    const float w0  = fmaxf(alpha[0], 0.0f);
    const float w1  = fmaxf(alpha[1], 0.0f);
    const float w2  = fmaxf(alpha[2], 0.0f);
    const float bia = fmaxf(beta[0], 0.0f);

    const float one_m = (1.0f - a) * (1.0f - a);
    const float coef  = 1.0f + a * a;
    const bool  fast  = (one_m == 0.0f);

    // v[b,t] = k[b,b,0,t,0]
    const float2* vrx = (const float2*)(k) + (size_t)(b1 * BDIM + b1) * NDIM * TDIM;
    const float2* vry = (const float2*)(k) + (size_t)(b2 * BDIM + b2) * NDIM * TDIM;

    // ---- vx (std_x) for elements t-1, t, t+1, t+2 — row-independent ----
    const float4 vx4 = ((const float4*)vrx)[tid];               // vx[t] (.x), vx[t+1] (.z)
    const float vxm  = vrx[max(t - 1, 0)].x;                    // clamped addr, masked below
    const float vxp  = vrx[min(t + 2, TDIM - 1)].x;
    const float sxm  = (tid == 0)       ? 0.0f : sqrtf(fmaxf(vxm, 0.0f));  // conv left pad
    const float sx0  = sqrtf(fmaxf(vx4.x, 0.0f));
    const float sx1  = sqrtf(fmaxf(vx4.z, 0.0f));
    const float sxp  = (tid == TPB - 1) ? 0.0f : sqrtf(fmaxf(vxp, 0.0f));  // conv right pad

    // ---- vy (std_y) for elements e0-1 .. e0+5, shared across the 4 rows ----
    // e0 = n0 + t is even -> 16B-aligned float4 loads over the float2 array.
    // Reads past row 0 of the (b2,b2) slice are in-bounds garbage, masked below.
    const int e0 = n0 + t;
    const float4 vyA = *(const float4*)(vry + e0);              // y(e0), y(e0+1)
    const float4 vyB = *(const float4*)(vry + e0 + 2);          // y(e0+2), y(e0+3)
    const float4 vyC = *(const float4*)(vry + e0 + 4);          // y(e0+4), y(e0+5)
    const float  ym  = vry[max(e0 - 1, 0)].x;                   // y(e0-1), clamped

    float sy[7];   // sy[j] = std_y at element e0-1+j ; fully unrolled -> registers
    {
        const float yv[7] = { ym, vyA.x, vyA.z, vyB.x, vyB.z, vyC.x, vyC.z };
        #pragma unroll
        for (int j = 0; j < 7; ++j) {
            const int e = e0 - 1 + j;
            const float y = (e >= 0 && e < TDIM) ? yv[j] : 0.0f;  // v_pad zeros
            sy[j] = sqrtf(fmaxf(y, 0.0f));
        }
    }

    // ---- per row: load k pairs t-1..t+2, recompute halo c-values, conv, store ----
    #pragma unroll
    for (int rl = 0; rl < ROWS; ++rl) {
        const float* krow = k + (size_t)(base + rl) * TDIM * 2;
        const float4 kv = ((const float4*)krow)[tid];                // k[t], k[t+1]
        const float2 kl = ((const float2*)krow)[max(t - 1, 0)];      // k[t-1] (clamped)
        const float2 kr = ((const float2*)krow)[min(t + 2, TDIM - 1)]; // k[t+2] (clamped)
        const float klg = (tid == 0)       ? 0.0f : kl.x;
        const float kln = (tid == 0)       ? 0.0f : kl.y;
        const float krg = (tid == TPB - 1) ? 0.0f : kr.x;
        const float krn = (tid == TPB - 1) ? 0.0f : kr.y;

        // element t+d of row rl uses vy index e0+rl+d -> sy[rl+d+1]
        float c0l, cnl, c00, cn0, c01, cn1, c0r, cnr;
        kfun(klg,  kln,  sxm, sy[rl + 0], one_m, coef, fast, c0l, cnl);
        kfun(kv.x, kv.y, sx0, sy[rl + 1], one_m, coef, fast, c00, cn0);
        kfun(kv.z, kv.w, sx1, sy[rl + 2], one_m, coef, fast, c01, cn1);
        kfun(krg,  krn,  sxp, sy[rl + 3], one_m, coef, fast, c0r, cnr);

        // kg = conv(c0) + bia ; kn = conv(cn) + kg
        const float kg0 = fmaf(w0, c0l, fmaf(w1, c00, fmaf(w2, c01, bia)));
        const float kg1 = fmaf(w0, c00, fmaf(w1, c01, fmaf(w2, c0r, bia)));
        const float kn0 = fmaf(w0, cnl, fmaf(w1, cn0, fmaf(w2, cn1, kg0)));
        const float kn1 = fmaf(w0, cn0, fmaf(w1, cn1, fmaf(w2, cnr, kg1)));

        float4 o;
        o.x = kg0; o.y = kn0; o.z = kg1; o.w = kn1;
        ((float4*)(out + (size_t)(base + rl) * TDIM * 2))[tid] = o;
    }
}

extern "C" void kernel_launch(void* const* d_in, const int* in_sizes, int n_in,
                              void* d_out, int out_size, void* d_ws, size_t ws_size,
                              hipStream_t stream) {
    const float* k     = (const float*)d_in[0];
    const float* leak  = (const float*)d_in[1];
    const float* alpha = (const float*)d_in[2];
    const float* beta  = (const float*)d_in[3];
    float* out = (float*)d_out;

    const int n_blocks = BDIM * BDIM * NDIM / ROWS;   // 2048
    conv_arccos_kernel<<<n_blocks, TPB, 0, stream>>>(k, leak, alpha, beta, out);
}

// Round 4
// 120.753 us; speedup vs baseline: 1.0755x; 1.0727x over previous
//
#include <hip/hip_runtime.h>
#include <math.h>

#define BDIM 8
#define NDIM 128
#define TDIM 1024
#define TPB 512
#define CT 64              // T-elements per chunk (32 pairs -> 32 threads/row)
#define RPI 16             // rows (n) handled per iteration = TPB / (CT/2)
#define NIT (NDIM / RPI)   // 8 n-iterations
#define SXN (CT + 2)       // std_x entries: t = tc-1 .. tc+CT
#define SYN (NDIM + CT + 1)// std_y entries: e = tc-1 .. tc+CT+NDIM-1  (193)

#define EPS_F 1e-12f
#define RHO_LIM_F (1.0f - 1e-6f)
#define PI_F 3.14159265358979323846f

// native vector type for nontemporal builtins (HIP_vector_type is rejected)
typedef float nfloat4 __attribute__((ext_vector_type(4)));

// Fast path identity (exact for all p >= 0 incl. p < eps):
//   p * clamp(kgp / max(p,eps), -RHO, RHO) == clamp(kgp, -p*RHO, p*RHO)
// so when one_m == (1-a)^2 == 0:  c0 = hc * med3(kgp, -p*RHO, p*RHO), no rcp.
// Pad elements pass k = 0 AND std = 0 -> c0 = cn = 0 on both paths.
__device__ __forceinline__ void kfun(float kgp, float kntk, float sx, float sy,
                                     float one_m, float coef, bool fast,
                                     float& c0, float& cn)
{
    const float inv2pi = 0.15915494309189535f;
    const float p = sx * sy;   // std_x * std_y, as in reference
    if (fast) {
        const float hc = 0.5f * coef;
        const float pr = p * RHO_LIM_F;
        c0 = hc * fminf(fmaxf(kgp, -pr), pr);   // v_med3_f32
        cn = hc * kntk;
    } else {
        const float r  = fminf(fmaxf(kgp * __builtin_amdgcn_rcpf(fmaxf(p, EPS_F)), -RHO_LIM_F), RHO_LIM_F);
        const float th = acosf(r);
        const float s  = sqrtf(1.0f - r * r);
        const float br = coef * PI_F - one_m * th;
        c0 = p * inv2pi * (one_m * s + r * br);
        cn = br * inv2pi * kntk;
    }
}

__global__ __launch_bounds__(TPB) void conv_arccos_kernel(
    const float* __restrict__ k,      // (B,B,N,T,2)
    const float* __restrict__ leak,   // scalar
    const float* __restrict__ alpha,  // (3,)
    const float* __restrict__ beta,   // scalar
    float* __restrict__ out)          // (B,B,N,T,2)
{
    __shared__ float sx_lds[SXN];     // std_x at t = tc-1+j
    __shared__ float sy_lds[SYN];     // std_y at e = tc-1+j  (0 beyond T: v_pad)

    const int chunk = blockIdx.x & 15;        // T-chunk (fastest -> blocks sharing bb adjacent)
    const int bb    = blockIdx.x >> 4;        // b1*8 + b2
    const int b2    = bb & (BDIM - 1);
    const int b1    = bb >> 3;
    const int tc    = chunk * CT;

    const int tid  = threadIdx.x;
    const int r_t  = tid & 31;                // thread-in-row (32 pairs per row-chunk)
    const int rsel = tid >> 5;                // 0..15: row-group

    // forward value of clamp_pg(x) is max(x, 0)
    const float a   = fmaxf(leak[0], 0.0f);
    const float w0  = fmaxf(alpha[0], 0.0f);
    const float w1  = fmaxf(alpha[1], 0.0f);
    const float w2  = fmaxf(alpha[2], 0.0f);
    const float bia = fmaxf(beta[0], 0.0f);

    const float one_m = (1.0f - a) * (1.0f - a);
    const float coef  = 1.0f + a * a;
    const bool  fast  = (one_m == 0.0f);

    // v[b,t] = k[b,b,0,t,0]
    const float2* vrx = (const float2*)k + (size_t)(b1 * BDIM + b1) * NDIM * TDIM;
    const float2* vry = (const float2*)k + (size_t)(b2 * BDIM + b2) * NDIM * TDIM;

    // ---- once per block: std tables into LDS (kills all sqrt/v-loads in hot loop) ----
    if (tid < SXN) {
        const int t = tc - 1 + tid;
        const float v = (t >= 0 && t < TDIM) ? vrx[t].x : 0.0f;   // conv/v_pad zeros
        sx_lds[tid] = sqrtf(fmaxf(v, 0.0f));
    } else if (tid < SXN + SYN) {
        const int j = tid - SXN;
        const int e = tc - 1 + j;
        const float v = (e >= 0 && e < TDIM) ? vry[e].x : 0.0f;   // v_pad zeros past T
        sy_lds[j] = sqrtf(fmaxf(v, 0.0f));
    }
    __syncthreads();   // the only barrier in the kernel

    // per-thread invariants
    const float sxm = sx_lds[2 * r_t];        // std_x(t0-1)
    const float sx0 = sx_lds[2 * r_t + 1];    // std_x(t0)
    const float sx1 = sx_lds[2 * r_t + 2];    // std_x(t0+1)
    const float sxp = sx_lds[2 * r_t + 3];    // std_x(t0+2)

    const int  t0     = tc + 2 * r_t;
    const bool lvalid = (t0 > 0);             // left conv-pad only at global t=0
    const bool rvalid = (t0 + 2 < TDIM);      // right conv-pad only at global t=1023
    const int  eli    = max(t0 - 1, 0);
    const int  eri    = min(t0 + 2, TDIM - 1);
    const int  f      = (tc >> 1) + r_t;      // float4 index within row

    #pragma unroll 2
    for (int i = 0; i < NIT; ++i) {
        const int n   = i * RPI + rsel;
        const int row = bb * NDIM + n;
        const float*  krow  = k + (size_t)row * (TDIM * 2);
        const float2* krow2 = (const float2*)krow;

        const nfloat4 kv = *((const nfloat4*)krow + f);   // (kgp,kntk) x2, 16B aligned
        const float2  kl = krow2[eli];                    // L1/L2-hot neighbor lines
        const float2  kr = krow2[eri];
        const float klg = lvalid ? kl.x : 0.0f;
        const float kln = lvalid ? kl.y : 0.0f;
        const float krg = rvalid ? kr.x : 0.0f;
        const float krn = rvalid ? kr.y : 0.0f;

        // std_y for elements t0-1 .. t0+2 of row n: 2-way LDS (free)
        const int jy = n + 2 * r_t + 1;
        const float sym = sy_lds[jy - 1];
        const float sy0 = sy_lds[jy];
        const float sy1 = sy_lds[jy + 1];
        const float syp = sy_lds[jy + 2];

        float c0l, cnl, c00, cn0, c01, cn1, c0r, cnr;
        kfun(klg,  kln,  sxm, sym, one_m, coef, fast, c0l, cnl);
        kfun(kv.x, kv.y, sx0, sy0, one_m, coef, fast, c00, cn0);
        kfun(kv.z, kv.w, sx1, sy1, one_m, coef, fast, c01, cn1);
        kfun(krg,  krn,  sxp, syp, one_m, coef, fast, c0r, cnr);

        // kg = conv(c0) + bia ; kn = conv(cn) + kg
        const float kg0 = fmaf(w0, c0l, fmaf(w1, c00, fmaf(w2, c01, bia)));
        const float kg1 = fmaf(w0, c00, fmaf(w1, c01, fmaf(w2, c0r, bia)));
        const float kn0 = fmaf(w0, cnl, fmaf(w1, cn0, fmaf(w2, cn1, kg0)));
        const float kn1 = fmaf(w0, cn0, fmaf(w1, cn1, fmaf(w2, cnr, kg1)));

        nfloat4 o;
        o.x = kg0; o.y = kn0; o.z = kg1; o.w = kn1;
        __builtin_nontemporal_store(o, (nfloat4*)(out + (size_t)row * (TDIM * 2)) + f);
    }
}

extern "C" void kernel_launch(void* const* d_in, const int* in_sizes, int n_in,
                              void* d_out, int out_size, void* d_ws, size_t ws_size,
                              hipStream_t stream) {
    const float* k     = (const float*)d_in[0];
    const float* leak  = (const float*)d_in[1];
    const float* alpha = (const float*)d_in[2];
    const float* beta  = (const float*)d_in[3];
    float* out = (float*)d_out;

    const int n_blocks = BDIM * BDIM * (TDIM / CT);   // 64 pairs x 16 chunks = 1024
    conv_arccos_kernel<<<n_blocks, TPB, 0, stream>>>(k, leak, alpha, beta, out);
}